// Round 3
// baseline (226.037 us; speedup 1.0000x reference)
//
#include <hip/hip_runtime.h>
#include <math.h>

// Gaussian blur 21x21, sigma=5, depthwise over [B=32, C=3, H=512, W=512] fp32,
// reflect padding, separable, fused single kernel.
//
// R3 (resubmit x2 after broker timeouts): LDS-conflict + instruction-count attack.
//   stage1: aligned float4 global->LDS for interior-x blocks (skewed tile),
//           scalar reflect path only for the 2/8 edge block-columns.
//   stage2: horizontal 21-tap, 4 outputs/thread, 7x float4 LDS loads (skew +2).
//   stage3: vertical 21-tap as scalar column sliding window: 1 col x 16 rows
//           per thread -> wave reads 64 consecutive floats/row = bank-conflict
//           free (2-way aliasing is free on gfx950). Replaces the 8-way
//           conflicted b128 pattern (s_h stride 64 = 0 mod 32 banks) of R2.
//   s_h stride padded 64->68 to stagger stage2 write banks.

#define KS    21
#define PAD   10
#define TILE  64
#define LW    (TILE + 2 * PAD)   // 84 tile rows (with halo)
#define SKEW  2                  // left skew so interior global float4 aligns
#define LWX   88                 // s_in row width: covers gx in [x0-12, x0+75]
#define SH    68                 // s_h padded row stride (64+4): bank stagger
#define IMG_H 512
#define IMG_W 512
#define NT    256

__global__ __launch_bounds__(NT) void gauss_blur_kernel(
    const float* __restrict__ in, float* __restrict__ out)
{
    __shared__ __align__(16) float s_in[LW * LWX];  // 84*88*4 = 29568 B
    __shared__ __align__(16) float s_h [LW * SH];   // 84*68*4 = 22848 B
    // total 52416 B -> 3 blocks/CU on 160 KiB LDS

    // Normalized 1-D Gaussian (outer-product normalization == 1-D norm squared)
    float w[KS];
    {
        float s = 0.f;
#pragma unroll
        for (int k = 0; k < KS; ++k) {
            float d = (float)(k - PAD);
            w[k] = expf(-d * d * (1.0f / 50.0f));  // 2*sigma^2 = 50
            s += w[k];
        }
        float inv = 1.0f / s;
#pragma unroll
        for (int k = 0; k < KS; ++k) w[k] *= inv;
    }

    const int tid   = threadIdx.x;
    const int plane = blockIdx.z;                 // b*C + c, 0..95
    const int x0    = blockIdx.x * TILE;
    const int y0    = blockIdx.y * TILE;
    const int xbase = x0 - PAD - SKEW;            // -12 .. 436, = 0 mod 4 floats

    const float* __restrict__ pin = in + (size_t)plane * (IMG_H * IMG_W);

    // ---- stage 1: global -> LDS ----
    if (xbase >= 0 && xbase + LWX <= IMG_W) {
        // interior in x: aligned float4 loads (y reflect still handled per row)
        for (int idx = tid; idx < LW * (LWX / 4); idx += NT) {
            int ly = idx / (LWX / 4);
            int q  = idx - ly * (LWX / 4);
            int gy = y0 + ly - PAD;
            gy = (gy < 0) ? -gy : ((gy >= IMG_H) ? (2 * IMG_H - 2 - gy) : gy);
            float4 v = *(const float4*)&pin[gy * IMG_W + xbase + 4 * q];
            *(float4*)&s_in[ly * LWX + 4 * q] = v;
        }
    } else {
        // x-edge blocks (bx==0 or 7): scalar reflect path
        for (int idx = tid; idx < LW * LWX; idx += NT) {
            int ly = idx / LWX;
            int j  = idx - ly * LWX;
            int gy = y0 + ly - PAD;
            int gx = xbase + j;
            gy = (gy < 0) ? -gy : ((gy >= IMG_H) ? (2 * IMG_H - 2 - gy) : gy);
            gx = (gx < 0) ? -gx : ((gx >= IMG_W) ? (2 * IMG_W - 2 - gx) : gx);
            s_in[idx] = pin[gy * IMG_W + gx];
        }
    }
    __syncthreads();

    // ---- stage 2: horizontal 21-tap, 4 outputs/thread ----
    // output col lx+d (d=0..3) needs s_in cols lx+2+d .. lx+22+d  (skew +2)
    for (int idx = tid; idx < LW * (TILE / 4); idx += NT) {
        int ly = idx >> 4;            // row 0..83
        int lx = (idx & 15) << 2;     // col 0,4,...,60
        const float4* rp = (const float4*)&s_in[ly * LWX + lx];  // aligned
        float v[28];
#pragma unroll
        for (int t = 0; t < 7; ++t) {
            float4 f = rp[t];
            v[4 * t + 0] = f.x; v[4 * t + 1] = f.y;
            v[4 * t + 2] = f.z; v[4 * t + 3] = f.w;
        }
        float a0 = 0.f, a1 = 0.f, a2 = 0.f, a3 = 0.f;
#pragma unroll
        for (int k = 0; k < KS; ++k) {
            float wk = w[k];
            a0 += wk * v[k + 2];
            a1 += wk * v[k + 3];
            a2 += wk * v[k + 4];
            a3 += wk * v[k + 5];
        }
        *(float4*)&s_h[ly * SH + lx] = make_float4(a0, a1, a2, a3);
    }
    __syncthreads();

    // ---- stage 3: vertical 21-tap, 1 col x 16 rows per thread ----
    // Wave lanes cover 64 consecutive columns -> ds_read_b32 2-way aliasing
    // only (free). Sliding accumulate: row rb+t feeds output r with tap t-r.
    {
        const int c  = tid & 63;              // column 0..63
        const int rb = (tid >> 6) << 4;       // row base 0,16,32,48

        float acc[16];
#pragma unroll
        for (int r = 0; r < 16; ++r) acc[r] = 0.f;

#pragma unroll
        for (int t = 0; t < KS + 15; ++t) {   // 36 s_h rows
            float v = s_h[(rb + t) * SH + c];
#pragma unroll
            for (int r = 0; r < 16; ++r) {
                int k = t - r;
                if (k >= 0 && k < KS) acc[r] += w[k] * v;
            }
        }

        float* __restrict__ pout = out + (size_t)plane * (IMG_H * IMG_W)
                                       + (size_t)(y0 + rb) * IMG_W + (x0 + c);
#pragma unroll
        for (int r = 0; r < 16; ++r) pout[r * IMG_W] = acc[r];  // 256B/wave
    }
}

extern "C" void kernel_launch(void* const* d_in, const int* in_sizes, int n_in,
                              void* d_out, int out_size, void* d_ws, size_t ws_size,
                              hipStream_t stream)
{
    const float* x = (const float*)d_in[0];
    float* out = (float*)d_out;

    dim3 grid(IMG_W / TILE, IMG_H / TILE, 96);   // 8 x 8 x (32*3) planes
    dim3 block(NT);
    gauss_blur_kernel<<<grid, block, 0, stream>>>(x, out);
}